// Round 9
// baseline (211.311 us; speedup 1.0000x reference)
//
#include <hip/hip_runtime.h>

typedef __bf16 bf16x8 __attribute__((ext_vector_type(8)));
typedef __bf16 bf16x2 __attribute__((ext_vector_type(2)));
typedef float  f32x16 __attribute__((ext_vector_type(16)));
typedef unsigned int u32x4 __attribute__((ext_vector_type(4)));

#define NB   2
#define SEQ  2048
#define NHQ  32
#define NHKV 8
#define HD   128
#define KVSTR 1024                 // floats between consecutive kv rows
#define NTILE 32                   // kv tiles of 64 per (b,hkv)
#define TILE_ELEMS 8192            // 64*128 bf16
#define TILE_BYTES 16384
#define SCL2E 0.12753599963140488f // (1/sqrt(128)) * log2(e)

static __device__ inline unsigned pk2(float a, float b) {
    bf16x2 t = {(__bf16)a, (__bf16)b};
    return __builtin_bit_cast(unsigned, t);
}

static __device__ inline void gload16(const void* g, void* l) {
    __builtin_amdgcn_global_load_lds(
        (const __attribute__((address_space(1))) unsigned*)g,
        (__attribute__((address_space(3))) unsigned*)l, 16, 0, 0);
}

// ---- prep: fp32 K,V -> bf16  K' pre-swizzled row-major, V' plain transposed
// K' elem: blk*8192 + row*128 + (d ^ ((row&15)<<3))
// V' elem: blk*8192 + d*64 + kv                         blk = (b*8+hkv)*32+t
__global__ __launch_bounds__(256) void prep_kv(
    const float* __restrict__ kg, const float* __restrict__ vg,
    __bf16* __restrict__ kws, __bf16* __restrict__ vws)
{
    __shared__ float vt[TILE_ELEMS];
    const int blk = blockIdx.x;
    const int tid = threadIdx.x;
    const int t   = blk & 31;
    const int bh  = blk >> 5;
    const int hkv = bh & 7;
    const int b   = bh >> 3;
    const float* ks = kg + (((size_t)b * SEQ + t * 64) * NHKV + hkv) * HD;
    const float* vs = vg + (((size_t)b * SEQ + t * 64) * NHKV + hkv) * HD;
    __bf16* kd = kws + (size_t)blk * TILE_ELEMS;
    __bf16* vd = vws + (size_t)blk * TILE_ELEMS;

    // K: thread handles row = tid>>2, 32 d's starting at (tid&3)*32
    {
        const int row = tid >> 2, ds0 = (tid & 3) * 32;
        const float* kr = ks + (size_t)row * KVSTR + ds0;
        const int X = (row & 15) << 3;
#pragma unroll
        for (int gI = 0; gI < 4; ++gI) {
            const float4 a = *(const float4*)(kr + gI * 8);
            const float4 c = *(const float4*)(kr + gI * 8 + 4);
            bf16x8 o = {(__bf16)a.x, (__bf16)a.y, (__bf16)a.z, (__bf16)a.w,
                        (__bf16)c.x, (__bf16)c.y, (__bf16)c.z, (__bf16)c.w};
            *(bf16x8*)&kd[row * 128 + ((ds0 + gI * 8) ^ X)] = o;
        }
    }
    // V: stage fp32 tile to LDS (coalesced), emit plain transposed
#pragma unroll
    for (int i = 0; i < 8; ++i) {
        const int e = (tid + i * 256) * 4;
        *(float4*)&vt[e] = *(const float4*)(vs + (size_t)(e >> 7) * KVSTR + (e & 127));
    }
    __syncthreads();
    {
        const int d = tid >> 1, kv0 = (tid & 1) * 32;
#pragma unroll
        for (int gI = 0; gI < 4; ++gI) {
            const int kv8 = kv0 + gI * 8;
            bf16x8 o;
#pragma unroll
            for (int j = 0; j < 8; ++j) o[j] = (__bf16)vt[(kv8 + j) * 128 + d];
            *(bf16x8*)&vd[d * 64 + kv8] = o;
        }
    }
}

// ---- main: K via LDS DMA dbuf; V direct from L2 into registers -------------
__global__ __launch_bounds__(512, 2) void gqa_attn_fwd(
    const float* __restrict__ qg, const __bf16* __restrict__ kws,
    const __bf16* __restrict__ vws, float* __restrict__ og)
{
    __shared__ __align__(16) __bf16 Kl[2][TILE_ELEMS];   // 32 KB total

    const int tid  = threadIdx.x;
    const int w    = tid >> 6;
    const int lane = tid & 63;
    const int l31  = lane & 31;
    const int hi   = lane >> 5;

    // R4 mapping (measured best): blocks c and c+256 complementary
    const int bid = blockIdx.x;
    const int qt  = (bid < 256) ? (7 - (bid >> 6)) : ((bid - 256) >> 6);
    const int sub = bid & 63;
    const int hq  = sub & 31;
    const int b   = sub >> 5;
    const int qb  = qt * 256;
    const int hkv = hq >> 2;

    const int ntiles = qt * 4 + 4;
    const int Tw     = qt * 4 + (w >> 1) + 1;    // this wave's active tiles

    // ---- Q fragments: lane owns q-row qb+32w+l31; B-frag k = 8*hi + j ------
    const int qrow = qb + w * 32 + l31;
    const float* qp = qg + (((size_t)b * SEQ + qrow) * NHQ + hq) * HD;
    bf16x8 bq[8];
#pragma unroll
    for (int s = 0; s < 8; ++s) {
        const int d0 = s * 16 + hi * 8;
        const float4 f0 = *(const float4*)(qp + d0);
        const float4 f1 = *(const float4*)(qp + d0 + 4);
        bf16x8 t = {(__bf16)f0.x, (__bf16)f0.y, (__bf16)f0.z, (__bf16)f0.w,
                    (__bf16)f1.x, (__bf16)f1.y, (__bf16)f1.z, (__bf16)f1.w};
        bq[s] = t;
    }

    // ---- K staging: 2 x global_load_lds(16B) per thread per tile -----------
    const char* kpb = (const char*)(kws + (size_t)((b * 8 + hkv) * NTILE) * TILE_ELEMS);
    const char* vpb = (const char*)(vws + (size_t)((b * 8 + hkv) * NTILE) * TILE_ELEMS);
    const int soff = w * 2048 + (lane << 4);
    const int doff = w * 2048;

    auto stageK = [&](int t, int buf) {
        const char* ksrc = kpb + (size_t)t * TILE_BYTES;
#pragma unroll
        for (int r = 0; r < 2; ++r)
            gload16(ksrc + soff + r * 1024, (char*)&Kl[buf][0] + doff + r * 1024);
    };

    // per-lane V' base: +db*4096 +ks*32 bytes gives bf16x8 at [d=db*32+l31][kv=ks*16+hi*8]
    const char* vlane = vpb + l31 * 128 + hi * 16;

    f32x16 acc[4] = {};       // acc[db]: O[q=crow(r,hi)][d=db*32+l31]
    float m_r = -1e30f, l_r = 0.f;   // scaled-log2 domain

    const int swk = (l31 & 15) << 3;   // K read swizzle (lane-constant)

    stageK(0, 0);                       // prologue

    for (int t = 0; t < ntiles; ++t) {
        const int cur = t & 1;
        asm volatile("s_waitcnt vmcnt(0)" ::: "memory");
        __builtin_amdgcn_s_barrier();   // tile t K landed; t-1 reads done
        __builtin_amdgcn_sched_barrier(0);
        if (t + 1 < ntiles) stageK(t + 1, cur ^ 1);   // lands under compute

        const bool active = (t < Tw);
        if (active) {
            const char* vt0 = vlane + (size_t)t * TILE_BYTES;

            // ---- swapped QK^T: S^T[kv][q], A=K, B=Q ------------------------
            f32x16 sf[2];
            __builtin_amdgcn_s_setprio(1);
#pragma unroll
            for (int kb = 0; kb < 2; ++kb) {
                sf[kb] = (f32x16)(0.f);
                const int krow = kb * 32 + l31;
#pragma unroll
                for (int s = 0; s < 8; ++s) {
                    const int d0 = s * 16 + hi * 8;
                    const bf16x8 ak = *(const bf16x8*)&Kl[cur][krow * 128 + (d0 ^ swk)];
                    sf[kb] = __builtin_amdgcn_mfma_f32_32x32x16_bf16(ak, bq[s], sf[kb], 0, 0, 0);
                }
            }
            __builtin_amdgcn_s_setprio(0);

            // ---- V batches 0,1 issued here: softmax covers L2 latency ------
            bf16x8 vbA[4], vbB[4];
#pragma unroll
            for (int db = 0; db < 4; ++db) vbA[db] = *(const bf16x8*)(vt0 + db * 4096);
#pragma unroll
            for (int db = 0; db < 4; ++db) vbB[db] = *(const bf16x8*)(vt0 + db * 4096 + 32);

            // ---- mask (raw domain), max tree, defer-rescale ----------------
            if (t == Tw - 1) {
#pragma unroll
                for (int kb = 0; kb < 2; ++kb)
#pragma unroll
                    for (int r = 0; r < 16; ++r) {
                        const int kvg = t * 64 + kb * 32 + ((r & 3) + ((r >> 2) << 3) + (hi << 2));
                        if (kvg > qrow) sf[kb][r] = -1e30f;
                    }
            }
            float t16[16];
#pragma unroll
            for (int r = 0; r < 16; ++r) t16[r] = fmaxf(sf[0][r], sf[1][r]);
#pragma unroll
            for (int r = 0; r < 8; ++r) t16[r] = fmaxf(t16[r], t16[r + 8]);
#pragma unroll
            for (int r = 0; r < 4; ++r) t16[r] = fmaxf(t16[r], t16[r + 4]);
            float pm = fmaxf(fmaxf(t16[0], t16[1]), fmaxf(t16[2], t16[3]));
            pm = fmaxf(pm, __shfl_xor(pm, 32));
            const float pms = pm * SCL2E;

            if (__any(pms - m_r > 8.0f)) {            // T13
                const float mn = fmaxf(m_r, pms);
                const float alpha = exp2f(m_r - mn);
                m_r = mn;
                l_r *= alpha;
#pragma unroll
                for (int r = 0; r < 16; ++r) {
                    const float ab = __shfl(alpha, (r & 3) + ((r >> 2) << 3) + (hi << 2));
#pragma unroll
                    for (int db = 0; db < 4; ++db) acc[db][r] *= ab;
                }
            }

            // ---- exp (scale folded into fma) + row sum ---------------------
            float p[2][16];
#pragma unroll
            for (int kb = 0; kb < 2; ++kb)
#pragma unroll
                for (int r = 0; r < 16; ++r)
                    p[kb][r] = exp2f(fmaf(sf[kb][r], SCL2E, -m_r));
            {
                float s16[16];
#pragma unroll
                for (int r = 0; r < 16; ++r) s16[r] = p[0][r] + p[1][r];
#pragma unroll
                for (int r = 0; r < 8; ++r) s16[r] += s16[r + 8];
#pragma unroll
                for (int r = 0; r < 4; ++r) s16[r] += s16[r + 4];
                float rs = (s16[0] + s16[1]) + (s16[2] + s16[3]);
                rs += __shfl_xor(rs, 32);
                l_r += rs;
            }

            // ---- T12: P -> bf16 A-frags via pack + permlane32_swap ---------
            bf16x8 pa[4];
#pragma unroll
            for (int ks2 = 0; ks2 < 4; ++ks2) {
                const int kb = ks2 >> 1, c = (ks2 & 1) * 8;
                unsigned x0 = pk2(p[kb][c + 0], p[kb][c + 1]);
                unsigned x1 = pk2(p[kb][c + 2], p[kb][c + 3]);
                unsigned y0 = pk2(p[kb][c + 4], p[kb][c + 5]);
                unsigned y1 = pk2(p[kb][c + 6], p[kb][c + 7]);
                asm volatile("v_permlane32_swap_b32 %0, %1" : "+v"(x0), "+v"(y0));
                asm volatile("v_permlane32_swap_b32 %0, %1" : "+v"(x1), "+v"(y1));
                u32x4 u = {x0, x1, y0, y1};
                pa[ks2] = __builtin_bit_cast(bf16x8, u);
            }

            // ---- PV (ks outer, V from regs, 2-deep batch pipeline) ---------
            __builtin_amdgcn_s_setprio(1);
#pragma unroll
            for (int db = 0; db < 4; ++db)
                acc[db] = __builtin_amdgcn_mfma_f32_32x32x16_bf16(pa[0], vbA[db], acc[db], 0, 0, 0);
#pragma unroll
            for (int db = 0; db < 4; ++db) vbA[db] = *(const bf16x8*)(vt0 + db * 4096 + 64);  // ks=2
#pragma unroll
            for (int db = 0; db < 4; ++db)
                acc[db] = __builtin_amdgcn_mfma_f32_32x32x16_bf16(pa[1], vbB[db], acc[db], 0, 0, 0);
#pragma unroll
            for (int db = 0; db < 4; ++db) vbB[db] = *(const bf16x8*)(vt0 + db * 4096 + 96);  // ks=3
#pragma unroll
            for (int db = 0; db < 4; ++db)
                acc[db] = __builtin_amdgcn_mfma_f32_32x32x16_bf16(pa[2], vbA[db], acc[db], 0, 0, 0);
#pragma unroll
            for (int db = 0; db < 4; ++db)
                acc[db] = __builtin_amdgcn_mfma_f32_32x32x16_bf16(pa[3], vbB[db], acc[db], 0, 0, 0);
            __builtin_amdgcn_s_setprio(0);
        }
    }

    // ---- epilogue: out = acc / l -------------------------------------------
    const float linv = 1.0f / l_r;
#pragma unroll
    for (int r = 0; r < 16; ++r) {
        const int crow = (r & 3) + ((r >> 2) << 3) + (hi << 2);
        const float lb = __shfl(linv, crow);
        const int qg_row = qb + w * 32 + crow;
        float* op = og + (((size_t)b * SEQ + qg_row) * NHQ + hq) * HD + l31;
#pragma unroll
        for (int db = 0; db < 4; ++db) op[db * 32] = acc[db][r] * lb;
    }
}

extern "C" void kernel_launch(void* const* d_in, const int* in_sizes, int n_in,
                              void* d_out, int out_size, void* d_ws, size_t ws_size,
                              hipStream_t stream) {
    const float* q = (const float*)d_in[0];
    const float* k = (const float*)d_in[1];
    const float* v = (const float*)d_in[2];
    float* out = (float*)d_out;
    __bf16* kws = (__bf16*)d_ws;
    __bf16* vws = kws + (size_t)NB * NHKV * NTILE * TILE_ELEMS;  // +8.39 MB

    prep_kv<<<dim3(NB * NHKV * NTILE), dim3(256), 0, stream>>>(k, v, kws, vws);
    gqa_attn_fwd<<<dim3((SEQ / 256) * NHQ * NB), dim3(512), 0, stream>>>(q, kws, vws, out);
}

// Round 10
// 118.298 us; speedup vs baseline: 1.7863x; 1.7863x over previous
//
#include <hip/hip_runtime.h>

typedef __bf16 bf16x8 __attribute__((ext_vector_type(8)));
typedef __bf16 bf16x2 __attribute__((ext_vector_type(2)));
typedef float  f32x16 __attribute__((ext_vector_type(16)));
typedef unsigned int u32x4 __attribute__((ext_vector_type(4)));

#define NB   2
#define SEQ  2048
#define NHQ  32
#define NHKV 8
#define HD   128
#define KVSTR 1024                 // floats between consecutive kv rows
#define NT32 64                    // kv tiles of 32 per (b,hkv)
#define TELEM 4096                 // 32*128 bf16 per tile
#define TBYTES 8192
#define SCL2E 0.12753599963140488f // (1/sqrt(128)) * log2(e)

static __device__ inline unsigned pk2(float a, float b) {
    bf16x2 t = {(__bf16)a, (__bf16)b};
    return __builtin_bit_cast(unsigned, t);
}

static __device__ inline void gload16(const void* g, void* l) {
    __builtin_amdgcn_global_load_lds(
        (const __attribute__((address_space(1))) unsigned*)g,
        (__attribute__((address_space(3))) unsigned*)l, 16, 0, 0);
}

// ---- prep: fp32 K,V -> bf16 FRAGMENT-MAJOR tiles of 32 kv ------------------
// K'' chunk c = (s,lane):   16B = K[kv=lane&31][d = s*16 + (lane>>5)*8 .. +7]
// V'' chunk c = (db,ks,lane): 16B = V[d=db*32+(lane&31)][kv = ks*16+(lane>>5)*8 ..+7]
// tile base = ((b*8+hkv)*64 + t32) * 4096 elems
__global__ __launch_bounds__(256) void prep_kv(
    const float* __restrict__ kg, const float* __restrict__ vg,
    __bf16* __restrict__ kws, __bf16* __restrict__ vws)
{
    __shared__ float st[32 * 128];   // 16 KB fp32 staging
    const int blk = blockIdx.x;      // = (b*8+hkv)*64 + t32
    const int tid = threadIdx.x;
    const int t32 = blk & 63;
    const int bh  = blk >> 6;
    const int hkv = bh & 7;
    const int b   = bh >> 3;
    const float* ks = kg + (((size_t)b * SEQ + t32 * 32) * NHKV + hkv) * HD;
    const float* vs = vg + (((size_t)b * SEQ + t32 * 32) * NHKV + hkv) * HD;
    __bf16* kd = kws + (size_t)blk * TELEM;
    __bf16* vd = vws + (size_t)blk * TELEM;

    // ---- K: stage fp32 tile coalesced, emit fragment-major chunks ----------
#pragma unroll
    for (int i = 0; i < 4; ++i) {
        const int e = (tid + i * 256) * 4;
        *(float4*)&st[e] = *(const float4*)(ks + (size_t)(e >> 7) * KVSTR + (e & 127));
    }
    __syncthreads();
#pragma unroll
    for (int i = 0; i < 2; ++i) {
        const int c = tid + i * 256;           // 512 chunks
        const int s = c >> 6, lane = c & 63;
        const int base = (lane & 31) * 128 + s * 16 + (lane >> 5) * 8;
        bf16x8 o;
#pragma unroll
        for (int j = 0; j < 8; ++j) o[j] = (__bf16)st[base + j];
        *(bf16x8*)&kd[c * 8] = o;
    }
    __syncthreads();
    // ---- V: stage fp32 tile coalesced, emit transposed fragment-major ------
#pragma unroll
    for (int i = 0; i < 4; ++i) {
        const int e = (tid + i * 256) * 4;
        *(float4*)&st[e] = *(const float4*)(vs + (size_t)(e >> 7) * KVSTR + (e & 127));
    }
    __syncthreads();
#pragma unroll
    for (int i = 0; i < 2; ++i) {
        const int c = tid + i * 256;           // 512 chunks
        const int db = c >> 7, ks2 = (c >> 6) & 1, lane = c & 63;
        const int d = db * 32 + (lane & 31);
        const int kv0 = ks2 * 16 + (lane >> 5) * 8;
        bf16x8 o;
#pragma unroll
        for (int j = 0; j < 8; ++j) o[j] = (__bf16)st[(kv0 + j) * 128 + d];
        *(bf16x8*)&vd[c * 8] = o;
    }
}

// ---- main: 4-wave blocks, 128-row q-tiles, KVBLK=32, frag-major LDS --------
__global__ __launch_bounds__(256, 3) void gqa_attn_fwd(
    const float* __restrict__ qg, const __bf16* __restrict__ kws,
    const __bf16* __restrict__ vws, float* __restrict__ og)
{
    __shared__ __align__(16) __bf16 Kl[2][TELEM];   // 16 KB
    __shared__ __align__(16) __bf16 Vt[2][TELEM];   // 16 KB

    const int tid  = threadIdx.x;
    const int w    = tid >> 6;        // wave 0..3
    const int lane = tid & 63;
    const int l31  = lane & 31;
    const int hi   = lane >> 5;

    // LPT: longest q-tiles dispatched first; 1024 blocks, ~3 resident/CU + pool
    const int bid = blockIdx.x;
    const int qt  = 15 - (bid >> 6);         // 0..15, 128-row q-tile
    const int sub = bid & 63;
    const int hq  = sub & 31;
    const int b   = sub >> 5;
    const int qb  = qt * 128;
    const int hkv = hq >> 2;

    const int ntiles = 4 * qt + 4;           // 32-kv tiles
    const int Tw     = 4 * qt + w + 1;       // this wave's active tiles

    // ---- Q fragments: lane owns q-row qb+32w+l31; B-frag k = 8*hi + j ------
    const int qrow = qb + w * 32 + l31;
    const float* qp = qg + (((size_t)b * SEQ + qrow) * NHQ + hq) * HD;
    bf16x8 bq[8];
#pragma unroll
    for (int s = 0; s < 8; ++s) {
        const int d0 = s * 16 + hi * 8;
        const float4 f0 = *(const float4*)(qp + d0);
        const float4 f1 = *(const float4*)(qp + d0 + 4);
        bf16x8 t = {(__bf16)f0.x, (__bf16)f0.y, (__bf16)f0.z, (__bf16)f0.w,
                    (__bf16)f1.x, (__bf16)f1.y, (__bf16)f1.z, (__bf16)f1.w};
        bq[s] = t;
    }

    // ---- DMA staging: 2+2 gload16 per thread per tile ----------------------
    const char* kpb = (const char*)(kws + (size_t)((b * 8 + hkv) * NT32) * TELEM);
    const char* vpb = (const char*)(vws + (size_t)((b * 8 + hkv) * NT32) * TELEM);
    const int off = tid * 16;

    auto stage = [&](int t, int buf) {
        const char* ksrc = kpb + (size_t)t * TBYTES;
        const char* vsrc = vpb + (size_t)t * TBYTES;
#pragma unroll
        for (int r = 0; r < 2; ++r)
            gload16(ksrc + off + r * 4096, (char*)&Kl[buf][0] + off + r * 4096);
#pragma unroll
        for (int r = 0; r < 2; ++r)
            gload16(vsrc + off + r * 4096, (char*)&Vt[buf][0] + off + r * 4096);
    };

    f32x16 acc[4] = {};       // acc[db]: O[q=crow(r,hi)][d=db*32+l31]
    float m_r = -1e30f, l_r = 0.f;   // scaled-log2 domain

    stage(0, 0);                       // prologue

    for (int t = 0; t < ntiles; ++t) {
        const int cur = t & 1;
        asm volatile("s_waitcnt vmcnt(0)" ::: "memory");
        __builtin_amdgcn_s_barrier();  // tile t landed; t-1 reads done
        __builtin_amdgcn_sched_barrier(0);
        if (t + 1 < ntiles) stage(t + 1, cur ^ 1);

        if (t < Tw) {
            // ---- swapped QK^T: S^T[kv 32][q 32], A=K frag-major ------------
            f32x16 sf = (f32x16)(0.f);
            __builtin_amdgcn_s_setprio(1);
#pragma unroll
            for (int s = 0; s < 8; ++s) {
                const bf16x8 ak = *(const bf16x8*)&Kl[cur][s * 512 + lane * 8];
                sf = __builtin_amdgcn_mfma_f32_32x32x16_bf16(ak, bq[s], sf, 0, 0, 0);
            }
            __builtin_amdgcn_s_setprio(0);

            // ---- causal mask on diagonal tile ------------------------------
            if (t == Tw - 1) {
#pragma unroll
                for (int r = 0; r < 16; ++r) {
                    const int kvg = t * 32 + ((r & 3) + ((r >> 2) << 3) + (hi << 2));
                    if (kvg > qrow) sf[r] = -1e30f;
                }
            }
            // ---- row max: in-register tree + cross-half --------------------
            float t8[8];
#pragma unroll
            for (int r = 0; r < 8; ++r) t8[r] = fmaxf(sf[r], sf[r + 8]);
#pragma unroll
            for (int r = 0; r < 4; ++r) t8[r] = fmaxf(t8[r], t8[r + 4]);
            float pm = fmaxf(fmaxf(t8[0], t8[1]), fmaxf(t8[2], t8[3]));
            pm = fmaxf(pm, __shfl_xor(pm, 32));
            const float pms = pm * SCL2E;

            if (__any(pms - m_r > 8.0f)) {            // T13 defer-rescale
                const float mn = fmaxf(m_r, pms);
                const float alpha = exp2f(m_r - mn);
                m_r = mn;
                l_r *= alpha;
#pragma unroll
                for (int r = 0; r < 16; ++r) {
                    const float ab = __shfl(alpha, (r & 3) + ((r >> 2) << 3) + (hi << 2));
#pragma unroll
                    for (int db = 0; db < 4; ++db) acc[db][r] *= ab;
                }
            }

            // ---- exp in place (scale folded) + row sum ---------------------
#pragma unroll
            for (int r = 0; r < 16; ++r)
                sf[r] = exp2f(fmaf(sf[r], SCL2E, -m_r));
            {
                float s8[8];
#pragma unroll
                for (int r = 0; r < 8; ++r) s8[r] = sf[r] + sf[r + 8];
#pragma unroll
                for (int r = 0; r < 4; ++r) s8[r] += s8[r + 4];
                float rs = (s8[0] + s8[1]) + (s8[2] + s8[3]);
                rs += __shfl_xor(rs, 32);
                l_r += rs;
            }

            // ---- T12: P -> bf16 A-frags via pack + permlane32_swap ---------
            bf16x8 pa[2];
#pragma unroll
            for (int ks2 = 0; ks2 < 2; ++ks2) {
                const int c = ks2 * 8;
                unsigned x0 = pk2(sf[c + 0], sf[c + 1]);
                unsigned x1 = pk2(sf[c + 2], sf[c + 3]);
                unsigned y0 = pk2(sf[c + 4], sf[c + 5]);
                unsigned y1 = pk2(sf[c + 6], sf[c + 7]);
                asm volatile("v_permlane32_swap_b32 %0, %1" : "+v"(x0), "+v"(y0));
                asm volatile("v_permlane32_swap_b32 %0, %1" : "+v"(x1), "+v"(y1));
                u32x4 u = {x0, x1, y0, y1};
                pa[ks2] = __builtin_bit_cast(bf16x8, u);
            }

            // ---- PV: acc[db] += P(32q x 32kv) * V(32kv x 32d), frag-major --
            __builtin_amdgcn_s_setprio(1);
#pragma unroll
            for (int db = 0; db < 4; ++db) {
#pragma unroll
                for (int ks2 = 0; ks2 < 2; ++ks2) {
                    const bf16x8 bv = *(const bf16x8*)&Vt[cur][(db * 2 + ks2) * 512 + lane * 8];
                    acc[db] = __builtin_amdgcn_mfma_f32_32x32x16_bf16(pa[ks2], bv, acc[db], 0, 0, 0);
                }
            }
            __builtin_amdgcn_s_setprio(0);
        }
    }

    // ---- epilogue: out = acc / l -------------------------------------------
    const float linv = 1.0f / l_r;
#pragma unroll
    for (int r = 0; r < 16; ++r) {
        const int crow = (r & 3) + ((r >> 2) << 3) + (hi << 2);
        const float lb = __shfl(linv, crow);
        const int qg_row = qb + w * 32 + crow;
        float* op = og + (((size_t)b * SEQ + qg_row) * NHQ + hq) * HD + l31;
#pragma unroll
        for (int db = 0; db < 4; ++db) op[db * 32] = acc[db][r] * lb;
    }
}

extern "C" void kernel_launch(void* const* d_in, const int* in_sizes, int n_in,
                              void* d_out, int out_size, void* d_ws, size_t ws_size,
                              hipStream_t stream) {
    const float* q = (const float*)d_in[0];
    const float* k = (const float*)d_in[1];
    const float* v = (const float*)d_in[2];
    float* out = (float*)d_out;
    __bf16* kws = (__bf16*)d_ws;
    __bf16* vws = kws + (size_t)NB * NHKV * NT32 * TELEM;  // +8.39 MB

    prep_kv<<<dim3(NB * NHKV * NT32), dim3(256), 0, stream>>>(k, v, kws, vws);
    gqa_attn_fwd<<<dim3((SEQ / 128) * NHQ * NB), dim3(256), 0, stream>>>(q, kws, vws, out);
}